// Round 11
// baseline (274.023 us; speedup 1.0000x reference)
//
#include <hip/hip_runtime.h>

typedef short bf16x8 __attribute__((ext_vector_type(8)));
typedef float f32x4 __attribute__((ext_vector_type(4)));

__device__ __forceinline__ unsigned short f2bf(float f) {
  unsigned int u = __float_as_uint(f);
  u += 0x7fffu + ((u >> 16) & 1u);
  return (unsigned short)(u >> 16);
}
__device__ __forceinline__ float bf2f(unsigned short h) {
  return __uint_as_float(((unsigned int)h) << 16);
}
__device__ __forceinline__ float lrelu(float a) { return a >= 0.f ? a : 0.2f * a; }

// ---------------- zero workspace region ----------------
__global__ void zero_kernel(int* __restrict__ p, int n) {
  int i = blockIdx.x * blockDim.x + threadIdx.x;
  int stride = gridDim.x * blockDim.x;
  for (; i < n; i += stride) p[i] = 0;
}

// ---- count+rank: standalone, NO LDS -> full occupancy; 8 edges/thread ----
__global__ __launch_bounds__(256) void count_rank_kernel(
    const int* __restrict__ dst, int* __restrict__ cnt, int* __restrict__ pw, int E) {
  int e = (blockIdx.x * blockDim.x + threadIdx.x) * 8;
  if (e + 8 <= E) {
    int4 d0 = *(const int4*)(dst + e);
    int4 d1 = *(const int4*)(dst + e + 4);
    int4 p0, p1;
    p0.x = atomicAdd(&cnt[d0.x], 1);
    p0.y = atomicAdd(&cnt[d0.y], 1);
    p0.z = atomicAdd(&cnt[d0.z], 1);
    p0.w = atomicAdd(&cnt[d0.w], 1);
    p1.x = atomicAdd(&cnt[d1.x], 1);
    p1.y = atomicAdd(&cnt[d1.y], 1);
    p1.z = atomicAdd(&cnt[d1.z], 1);
    p1.w = atomicAdd(&cnt[d1.w], 1);
    *(int4*)(pw + e) = p0;
    *(int4*)(pw + e + 4) = p1;
  } else {
    for (; e < E; ++e) pw[e] = atomicAdd(&cnt[dst[e]], 1);
  }
}

// ---- GEMM + fused attention scalars ----
__global__ __launch_bounds__(256) void gemm_kernel(
    const float* __restrict__ x, const float* __restrict__ w,
    const float* __restrict__ emb,
    const float* __restrict__ att_i, const float* __restrict__ att_j,
    const float* __restrict__ att_em_i, const float* __restrict__ att_em_j,
    unsigned short* __restrict__ xl, float* __restrict__ ai, float* __restrict__ aj,
    int n) {
  __shared__ __align__(16) unsigned short xs[64 * 128];   // 16 KB, swizzled
  __shared__ __align__(16) unsigned short wl[128 * 128];  // 32 KB, swizzled
  const int t = threadIdx.x;
  const int r0 = blockIdx.x * 64;
  // stage W (128x128 f32 -> bf16)
#pragma unroll
  for (int i = 0; i < 16; ++i) {
    int f4 = t + i * 256;
    int row = f4 >> 5;
    int kk = (f4 & 31) << 2;
    float4 v = *(const float4*)(w + row * 128 + kk);
    ushort4 b;
    b.x = f2bf(v.x); b.y = f2bf(v.y); b.z = f2bf(v.z); b.w = f2bf(v.w);
    int boff = (kk << 1) ^ ((row & 7) << 4);
    *(ushort4*)((char*)wl + row * 256 + boff) = b;
  }
  // stage x tile (64 rows)
#pragma unroll
  for (int i = 0; i < 8; ++i) {
    int f4 = t + i * 256;
    int row = f4 >> 5;
    int kk = (f4 & 31) << 2;
    int gr = r0 + row;
    float4 v;
    if (gr < n) v = *(const float4*)(x + gr * 128 + kk);
    else { v.x = 0.f; v.y = 0.f; v.z = 0.f; v.w = 0.f; }
    ushort4 b;
    b.x = f2bf(v.x); b.y = f2bf(v.y); b.z = f2bf(v.z); b.w = f2bf(v.w);
    int boff = (kk << 1) ^ ((row & 7) << 4);
    *(ushort4*)((char*)xs + row * 256 + boff) = b;
  }
  __syncthreads();
  const int wid = t >> 6, lane = t & 63;
  const int m16 = lane & 15, kg = lane >> 4;
  const int arow = wid * 16 + m16;
  const f32x4 vzero = {0.f, 0.f, 0.f, 0.f};
  f32x4 acc[8];
#pragma unroll
  for (int i = 0; i < 8; ++i) acc[i] = vzero;
#pragma unroll
  for (int s = 0; s < 4; ++s) {
    int kb = s * 64 + kg * 16;
    bf16x8 a = *(const bf16x8*)((const char*)xs + arow * 256 + (kb ^ ((arow & 7) << 4)));
#pragma unroll
    for (int cf = 0; cf < 8; ++cf) {
      int wrow = cf * 16 + m16;
      bf16x8 b = *(const bf16x8*)((const char*)wl + wrow * 256 + (kb ^ ((wrow & 7) << 4)));
      acc[cf] = __builtin_amdgcn_mfma_f32_16x16x32_bf16(a, b, acc[cf], 0, 0, 0);
    }
  }
  // C/D layout: col = cf*16 + (lane&15), row = wid*16 + (lane>>4)*4 + q
  const int crow0 = wid * 16 + kg * 4;
#pragma unroll
  for (int q = 0; q < 4; ++q) {
    int gr = r0 + crow0 + q;
    if (gr < n) {
#pragma unroll
      for (int cf = 0; cf < 8; ++cf)
        xl[gr * 128 + cf * 16 + m16] = f2bf(acc[cf][q]);
    }
  }
  // ---- fused ai/aj epilogue ----
  float ati[8], atj[8];
#pragma unroll
  for (int cf = 0; cf < 8; ++cf) {
    ati[cf] = att_i[cf * 16 + m16];
    atj[cf] = att_j[cf * 16 + m16];
  }
  float4 aemi0 = *(const float4*)(att_em_i + m16 * 8);
  float4 aemi1 = *(const float4*)(att_em_i + m16 * 8 + 4);
  float4 aemj0 = *(const float4*)(att_em_j + m16 * 8);
  float4 aemj1 = *(const float4*)(att_em_j + m16 * 8 + 4);
#pragma unroll
  for (int q = 0; q < 4; ++q) {
    int gr = r0 + crow0 + q;
    if (gr < n) {
      float si = 0.f, sj = 0.f;
#pragma unroll
      for (int cf = 0; cf < 8; ++cf) {
        si += acc[cf][q] * ati[cf];
        sj += acc[cf][q] * atj[cf];
      }
      const float* ep = emb + (size_t)gr * 128 + m16 * 8;
      float4 e0 = *(const float4*)(ep);
      float4 e1 = *(const float4*)(ep + 4);
      si += e0.x * aemi0.x + e0.y * aemi0.y + e0.z * aemi0.z + e0.w * aemi0.w
          + e1.x * aemi1.x + e1.y * aemi1.y + e1.z * aemi1.z + e1.w * aemi1.w;
      sj += e0.x * aemj0.x + e0.y * aemj0.y + e0.z * aemj0.z + e0.w * aemj0.w
          + e1.x * aemj1.x + e1.y * aemj1.y + e1.z * aemj1.z + e1.w * aemj1.w;
#pragma unroll
      for (int off = 1; off < 16; off <<= 1) {
        si += __shfl_xor(si, off);
        sj += __shfl_xor(sj, off);
      }
      if (m16 == 0) { ai[gr] = si; aj[gr] = sj; }
    }
  }
}

// multi-block scan, step 1: per-block exclusive scan + block sums
__global__ __launch_bounds__(1024) void scan1_kernel(
    const int* __restrict__ cnt, int* __restrict__ rp, int* __restrict__ bsum, int n) {
  __shared__ int wsum[16];
  int t = threadIdx.x, lane = t & 63, wid = t >> 6;
  int i = blockIdx.x * 1024 + t;
  int v = (i < n) ? cnt[i] : 0;
  int incl = v;
#pragma unroll
  for (int off = 1; off < 64; off <<= 1) {
    int u = __shfl_up(incl, off);
    if (lane >= off) incl += u;
  }
  if (lane == 63) wsum[wid] = incl;
  __syncthreads();
  if (t < 16) {
    int wv = wsum[t];
    int winc = wv;
#pragma unroll
    for (int off = 1; off < 16; off <<= 1) {
      int u = __shfl_up(winc, off);
      if (t >= off) winc += u;
    }
    wsum[t] = winc - wv;  // exclusive wave offset
  }
  __syncthreads();
  int excl = wsum[wid] + incl - v;
  if (i < n) rp[i] = excl;
  if (t == 1023) bsum[blockIdx.x] = excl + v;
}

// scan step 2 (fused lookback): add block prefix; last block writes rp[n]
__global__ __launch_bounds__(256) void scan3_kernel(
    const int* __restrict__ bsum, int* __restrict__ rp, int n, int nb) {
  int lane = threadIdx.x & 63;
  int bb = blockIdx.x >> 2;  // owning scan1 block (1024 = 4*256)
  int pref = 0, tot = 0;
  for (int base = 0; base < nb; base += 64) {
    int idx = base + lane;
    int v = (idx < nb) ? bsum[idx] : 0;
    int p = (idx < bb) ? v : 0;
#pragma unroll
    for (int off = 32; off > 0; off >>= 1) {
      p += __shfl_xor(p, off);
      v += __shfl_xor(v, off);
    }
    pref += p;
    tot += v;
  }
  int i = blockIdx.x * 256 + threadIdx.x;
  if (i < n) rp[i] += pref;
  if (blockIdx.x == gridDim.x - 1 && threadIdx.x == 0) rp[n] = tot;
}

// atomic-free scatter: pos = rp[dst] + precomputed rank; 8 edges/thread
__global__ __launch_bounds__(256) void scatter_kernel(
    const int* __restrict__ src, const int* __restrict__ dst,
    const int* __restrict__ rp, const int* __restrict__ pw,
    int* __restrict__ csr, int E) {
  int e = (blockIdx.x * blockDim.x + threadIdx.x) * 8;
  if (e + 8 <= E) {
    int4 s0 = *(const int4*)(src + e);
    int4 s1 = *(const int4*)(src + e + 4);
    int4 d0 = *(const int4*)(dst + e);
    int4 d1 = *(const int4*)(dst + e + 4);
    int4 p0 = *(const int4*)(pw + e);
    int4 p1 = *(const int4*)(pw + e + 4);
    int r0 = rp[d0.x], r1 = rp[d0.y], r2 = rp[d0.z], r3 = rp[d0.w];
    int r4 = rp[d1.x], r5 = rp[d1.y], r6 = rp[d1.z], r7 = rp[d1.w];
    csr[r0 + p0.x] = s0.x;
    csr[r1 + p0.y] = s0.y;
    csr[r2 + p0.z] = s0.z;
    csr[r3 + p0.w] = s0.w;
    csr[r4 + p1.x] = s1.x;
    csr[r5 + p1.y] = s1.y;
    csr[r6 + p1.z] = s1.z;
    csr[r7 + p1.w] = s1.w;
  } else {
    for (; e < E; ++e) csr[rp[dst[e]] + pw[e]] = src[e];
  }
}

// ---------------- fused softmax+aggregation + BN partial stats ----------------
// One wave per node; single-pass no-max softmax (logits bounded for this data);
// csr chunk prefetch; ROW-MAJOR coalesced BN column partials in epilogue.
__global__ __launch_bounds__(256) void agg_kernel(
    const float* __restrict__ ai, const float* __restrict__ aj,
    const unsigned short* __restrict__ xl,
    const int* __restrict__ row_ptr, const int* __restrict__ csr_src,
    const float* __restrict__ bias, float* __restrict__ out,
    float* __restrict__ pS, float* __restrict__ pQ, int n) {
  __shared__ float2 red_s[4][64];
  __shared__ float2 red_q[4][64];
  int wid = threadIdx.x >> 6, lane = threadIdx.x & 63;
  int node = blockIdx.x * 4 + wid;
  bool active = node < n;
  int beg = 0, end = 0;
  float ain = 0.f, w_self = 0.f;
  if (active) {
    beg = row_ptr[node];
    end = row_ptr[node + 1];
    ain = ai[node];
    w_self = __expf(lrelu(ain + aj[node]));
  }
  float dl = 0.f, acc0 = 0.f, acc1 = 0.f;
  const int c0 = lane * 2;
  int s = 0;
  if (beg + lane < end) s = csr_src[beg + lane];
  for (int cs = beg; cs < end; cs += 64) {
    int ce = min(64, end - cs);
    float we = 0.f;
    if (lane < ce) we = __expf(lrelu(ain + aj[s]));
    dl += we;
    // prefetch next chunk's indices before the latency-heavy gather loop
    int s_nxt = 0;
    if (cs + 64 + lane < end) s_nxt = csr_src[cs + 64 + lane];
    int j = 0;
    for (; j + 8 <= ce; j += 8) {
      float w0 = __shfl(we, j),     w1 = __shfl(we, j + 1);
      float w2 = __shfl(we, j + 2), w3 = __shfl(we, j + 3);
      float w4 = __shfl(we, j + 4), w5 = __shfl(we, j + 5);
      float w6 = __shfl(we, j + 6), w7 = __shfl(we, j + 7);
      int i0 = __shfl(s, j),     i1 = __shfl(s, j + 1);
      int i2 = __shfl(s, j + 2), i3 = __shfl(s, j + 3);
      int i4 = __shfl(s, j + 4), i5 = __shfl(s, j + 5);
      int i6 = __shfl(s, j + 6), i7 = __shfl(s, j + 7);
      ushort2 v0 = *(const ushort2*)(xl + (size_t)i0 * 128 + c0);
      ushort2 v1 = *(const ushort2*)(xl + (size_t)i1 * 128 + c0);
      ushort2 v2 = *(const ushort2*)(xl + (size_t)i2 * 128 + c0);
      ushort2 v3 = *(const ushort2*)(xl + (size_t)i3 * 128 + c0);
      ushort2 v4 = *(const ushort2*)(xl + (size_t)i4 * 128 + c0);
      ushort2 v5 = *(const ushort2*)(xl + (size_t)i5 * 128 + c0);
      ushort2 v6 = *(const ushort2*)(xl + (size_t)i6 * 128 + c0);
      ushort2 v7 = *(const ushort2*)(xl + (size_t)i7 * 128 + c0);
      acc0 += w0 * bf2f(v0.x); acc1 += w0 * bf2f(v0.y);
      acc0 += w1 * bf2f(v1.x); acc1 += w1 * bf2f(v1.y);
      acc0 += w2 * bf2f(v2.x); acc1 += w2 * bf2f(v2.y);
      acc0 += w3 * bf2f(v3.x); acc1 += w3 * bf2f(v3.y);
      acc0 += w4 * bf2f(v4.x); acc1 += w4 * bf2f(v4.y);
      acc0 += w5 * bf2f(v5.x); acc1 += w5 * bf2f(v5.y);
      acc0 += w6 * bf2f(v6.x); acc1 += w6 * bf2f(v6.y);
      acc0 += w7 * bf2f(v7.x); acc1 += w7 * bf2f(v7.y);
    }
    for (; j < ce; ++j) {
      float wj = __shfl(we, j);
      int ij = __shfl(s, j);
      ushort2 v = *(const ushort2*)(xl + (size_t)ij * 128 + c0);
      acc0 += wj * bf2f(v.x); acc1 += wj * bf2f(v.y);
    }
    s = s_nxt;
  }
#pragma unroll
  for (int off = 32; off > 0; off >>= 1) dl += __shfl_xor(dl, off);
  float inv = 1.f / (dl + w_self + 1e-16f);
  float2 o; o.x = 0.f; o.y = 0.f;
  if (active) {
    ushort2 u = *(const ushort2*)(xl + (size_t)node * 128 + c0);
    o.x = (acc0 + w_self * bf2f(u.x)) * inv + bias[c0];
    o.y = (acc1 + w_self * bf2f(u.y)) * inv + bias[c0 + 1];
    *(float2*)(out + (size_t)node * 128 + c0) = o;
  }
  // ---- BN partials: block column sums, ROW-MAJOR pS[block][c] (coalesced) ----
  red_s[wid][lane] = o;
  float2 oq; oq.x = o.x * o.x; oq.y = o.y * o.y;
  red_q[wid][lane] = oq;
  __syncthreads();
  int t = threadIdx.x;
  if (t < 128) {
    int l = t >> 1, cm = t & 1;
    float ssum = 0.f;
#pragma unroll
    for (int w = 0; w < 4; ++w) ssum += cm ? red_s[w][l].y : red_s[w][l].x;
    pS[(size_t)blockIdx.x * 128 + t] = ssum;
  } else {
    int tt = t - 128;
    int l = tt >> 1, cm = tt & 1;
    float qsum = 0.f;
#pragma unroll
    for (int w = 0; w < 4; ++w) qsum += cm ? red_q[w][l].y : red_q[w][l].x;
    pQ[(size_t)blockIdx.x * 128 + tt] = qsum;
  }
}

// BN reduce stage 1: 128 blocks; coalesced row reads, one thread per column
__global__ __launch_bounds__(256) void bn_b1_kernel(
    const float* __restrict__ pS, const float* __restrict__ pQ,
    float* __restrict__ p2S, float* __restrict__ p2Q, int nb) {
  __shared__ float comb[2][128];
  int t = threadIdx.x;
  int c = t & 127, half = t >> 7;
  int chunk = (nb + gridDim.x - 1) / gridDim.x;
  int start = blockIdx.x * chunk;
  int end = min(nb, start + chunk);
  float s = 0.f, qv = 0.f;
  for (int r = start + half; r < end; r += 2) {
    s += pS[(size_t)r * 128 + c];
    qv += pQ[(size_t)r * 128 + c];
  }
  comb[half][c] = s;
  __syncthreads();
  if (t < 128) p2S[(size_t)blockIdx.x * 128 + t] = comb[0][t] + comb[1][t];
  __syncthreads();
  comb[half][c] = qv;
  __syncthreads();
  if (t >= 128) p2Q[(size_t)blockIdx.x * 128 + (t - 128)] = comb[0][t - 128] + comb[1][t - 128];
}

// BN reduce stage 2: single block; 128 rows of p2
__global__ __launch_bounds__(256) void bn_b2_kernel(
    const float* __restrict__ p2S, const float* __restrict__ p2Q,
    float* __restrict__ sums, float* __restrict__ sumsq, int nb2) {
  int t = threadIdx.x;
  int c = t & 127;
  float acc = 0.f;
  if (t < 128) {
    for (int r = 0; r < nb2; ++r) acc += p2S[(size_t)r * 128 + c];
    sums[c] = acc;
  } else {
    for (int r = 0; r < nb2; ++r) acc += p2Q[(size_t)r * 128 + c];
    sumsq[c] = acc;
  }
}

__global__ __launch_bounds__(256) void bnapply_kernel(
    float* __restrict__ out, const float* __restrict__ sums,
    const float* __restrict__ sumsq, const float* __restrict__ gamma,
    const float* __restrict__ beta, int n, float invN) {
  int q = threadIdx.x & 31;
  int rs = threadIdx.x >> 5;
  int c = q * 4;
  float4 mu, var, sc, sh;
  mu.x = sums[c + 0] * invN; mu.y = sums[c + 1] * invN;
  mu.z = sums[c + 2] * invN; mu.w = sums[c + 3] * invN;
  var.x = sumsq[c + 0] * invN - mu.x * mu.x;
  var.y = sumsq[c + 1] * invN - mu.y * mu.y;
  var.z = sumsq[c + 2] * invN - mu.z * mu.z;
  var.w = sumsq[c + 3] * invN - mu.w * mu.w;
  sc.x = rsqrtf(var.x + 1e-5f) * gamma[c + 0];
  sc.y = rsqrtf(var.y + 1e-5f) * gamma[c + 1];
  sc.z = rsqrtf(var.z + 1e-5f) * gamma[c + 2];
  sc.w = rsqrtf(var.w + 1e-5f) * gamma[c + 3];
  sh.x = beta[c + 0] - mu.x * sc.x;
  sh.y = beta[c + 1] - mu.y * sc.y;
  sh.z = beta[c + 2] - mu.z * sc.z;
  sh.w = beta[c + 3] - mu.w * sc.w;
  for (int r = blockIdx.x * 8 + rs; r < n; r += gridDim.x * 8) {
    float4 v = *(const float4*)(out + (size_t)r * 128 + c);
    v.x = v.x * sc.x + sh.x;
    v.y = v.y * sc.y + sh.y;
    v.z = v.z * sc.z + sh.z;
    v.w = v.w * sc.w + sh.w;
    *(float4*)(out + (size_t)r * 128 + c) = v;
  }
}

extern "C" void kernel_launch(void* const* d_in, const int* in_sizes, int n_in,
                              void* d_out, int out_size, void* d_ws, size_t ws_size,
                              hipStream_t stream) {
  (void)n_in; (void)out_size; (void)ws_size;
  const float* x = (const float*)d_in[0];
  const int* ei = (const int*)d_in[1];
  const float* emb = (const float*)d_in[2];
  const float* lin_w = (const float*)d_in[3];
  const float* att_i = (const float*)d_in[4];
  const float* att_j = (const float*)d_in[5];
  const float* att_em_i = (const float*)d_in[6];
  const float* att_em_j = (const float*)d_in[7];
  const float* bias = (const float*)d_in[8];
  const float* gamma = (const float*)d_in[9];
  const float* beta = (const float*)d_in[10];
  float* out = (float*)d_out;
  const int N = in_sizes[0] / 128;
  const int E = in_sizes[1] / 2;
  const int* src = ei;
  const int* dst = ei + E;
  const int NB = (N + 1023) / 1024;        // scan1 blocks
  const int NBG = (N + 63) / 64;           // gemm blocks
  const int NBC = (E / 8 + 255) / 256 + 1; // count blocks (8 edges/thread)
  const int NBAG = (N + 3) / 4;            // agg blocks (4 nodes/block)
  const int NB1 = 128;                     // bn reduce stage-1 blocks

  auto align_up = [](size_t v) { return (v + 255) & ~(size_t)255; };
  size_t off = 0;
  size_t xl_off = off;    off = align_up(off + (size_t)N * 128 * 2);
  size_t ai_off = off;    off = align_up(off + (size_t)N * 4);
  size_t aj_off = off;    off = align_up(off + (size_t)N * 4);
  size_t rp_off = off;    off = align_up(off + (size_t)(N + 1) * 4);
  size_t csr_off = off;   off = align_up(off + (size_t)E * 4);
  size_t pw_off = off;    off = align_up(off + (size_t)E * 4);
  size_t bsum_off = off;  off = align_up(off + (size_t)(NB + 1) * 4);
  size_t pS_off = off;    off = align_up(off + (size_t)NBAG * 128 * 4);
  size_t pQ_off = off;    off = align_up(off + (size_t)NBAG * 128 * 4);
  size_t p2S_off = off;   off = align_up(off + (size_t)NB1 * 128 * 4);
  size_t p2Q_off = off;   off = align_up(off + (size_t)NB1 * 128 * 4);
  size_t sums_off = off;  off = align_up(off + 512);
  size_t sumsq_off = off; off = align_up(off + 512);
  size_t cnt_off = off;   off = align_up(off + (size_t)N * 4);

  char* ws = (char*)d_ws;
  unsigned short* xl = (unsigned short*)(ws + xl_off);
  float* ai = (float*)(ws + ai_off);
  float* aj = (float*)(ws + aj_off);
  int* rp = (int*)(ws + rp_off);
  int* csr = (int*)(ws + csr_off);
  int* pw = (int*)(ws + pw_off);
  int* bsum = (int*)(ws + bsum_off);
  float* pS = (float*)(ws + pS_off);
  float* pQ = (float*)(ws + pQ_off);
  float* p2S = (float*)(ws + p2S_off);
  float* p2Q = (float*)(ws + p2Q_off);
  float* sums = (float*)(ws + sums_off);
  float* sumsq = (float*)(ws + sumsq_off);
  int* cnt = (int*)(ws + cnt_off);

  hipLaunchKernelGGL(zero_kernel, dim3((N + 255) / 256), dim3(256), 0, stream,
                     cnt, N);
  hipLaunchKernelGGL(count_rank_kernel, dim3(NBC), dim3(256), 0, stream,
                     dst, cnt, pw, E);
  hipLaunchKernelGGL(gemm_kernel, dim3(NBG), dim3(256), 0, stream,
                     x, lin_w, emb, att_i, att_j, att_em_i, att_em_j,
                     xl, ai, aj, N);
  hipLaunchKernelGGL(scan1_kernel, dim3(NB), dim3(1024), 0, stream, cnt, rp, bsum, N);
  hipLaunchKernelGGL(scan3_kernel, dim3((N + 255) / 256), dim3(256), 0, stream,
                     bsum, rp, N, NB);
  hipLaunchKernelGGL(scatter_kernel, dim3((E / 8 + 255) / 256 + 1), dim3(256), 0,
                     stream, src, dst, rp, pw, csr, E);
  hipLaunchKernelGGL(agg_kernel, dim3(NBAG), dim3(256), 0, stream,
                     ai, aj, xl, rp, csr, bias, out, pS, pQ, N);
  hipLaunchKernelGGL(bn_b1_kernel, dim3(NB1), dim3(256), 0, stream,
                     pS, pQ, p2S, p2Q, NBAG);
  hipLaunchKernelGGL(bn_b2_kernel, dim3(1), dim3(256), 0, stream,
                     p2S, p2Q, sums, sumsq, NB1);
  hipLaunchKernelGGL(bnapply_kernel, dim3(2048), dim3(256), 0, stream,
                     out, sums, sumsq, gamma, beta, N, 1.0f / (float)N);
}

// Round 12
// 236.487 us; speedup vs baseline: 1.1587x; 1.1587x over previous
//
#include <hip/hip_runtime.h>

typedef short bf16x8 __attribute__((ext_vector_type(8)));
typedef float f32x4 __attribute__((ext_vector_type(4)));

__device__ __forceinline__ unsigned short f2bf(float f) {
  unsigned int u = __float_as_uint(f);
  u += 0x7fffu + ((u >> 16) & 1u);
  return (unsigned short)(u >> 16);
}
__device__ __forceinline__ float bf2f(unsigned short h) {
  return __uint_as_float(((unsigned int)h) << 16);
}
__device__ __forceinline__ float lrelu(float a) { return a >= 0.f ? a : 0.2f * a; }

#define BN_PS 1568  // padded partial stride (>= nblocksA)

// ---------------- zero workspace region ----------------
__global__ void zero_kernel(int* __restrict__ p, int n) {
  int i = blockIdx.x * blockDim.x + threadIdx.x;
  int stride = gridDim.x * blockDim.x;
  for (; i < n; i += stride) p[i] = 0;
}

// ---- GEMM + fused attention scalars:
//   xl[n,c] = bf16( sum_k x[n,k] * W[c,k] )
//   ai[n] = <xl[n],att_i> + <emb[n],att_em_i>;  aj[n] likewise
__global__ __launch_bounds__(256) void gemm_kernel(
    const float* __restrict__ x, const float* __restrict__ w,
    const float* __restrict__ emb,
    const float* __restrict__ att_i, const float* __restrict__ att_j,
    const float* __restrict__ att_em_i, const float* __restrict__ att_em_j,
    unsigned short* __restrict__ xl, float* __restrict__ ai, float* __restrict__ aj,
    int n) {
  __shared__ __align__(16) unsigned short xs[64 * 128];   // 16 KB, swizzled
  __shared__ __align__(16) unsigned short wl[128 * 128];  // 32 KB, swizzled
  const int t = threadIdx.x;
  const int r0 = blockIdx.x * 64;
  // stage W (128x128 f32 -> bf16)
#pragma unroll
  for (int i = 0; i < 16; ++i) {
    int f4 = t + i * 256;
    int row = f4 >> 5;
    int kk = (f4 & 31) << 2;
    float4 v = *(const float4*)(w + row * 128 + kk);
    ushort4 b;
    b.x = f2bf(v.x); b.y = f2bf(v.y); b.z = f2bf(v.z); b.w = f2bf(v.w);
    int boff = (kk << 1) ^ ((row & 7) << 4);
    *(ushort4*)((char*)wl + row * 256 + boff) = b;
  }
  // stage x tile (64 rows)
#pragma unroll
  for (int i = 0; i < 8; ++i) {
    int f4 = t + i * 256;
    int row = f4 >> 5;
    int kk = (f4 & 31) << 2;
    int gr = r0 + row;
    float4 v;
    if (gr < n) v = *(const float4*)(x + gr * 128 + kk);
    else { v.x = 0.f; v.y = 0.f; v.z = 0.f; v.w = 0.f; }
    ushort4 b;
    b.x = f2bf(v.x); b.y = f2bf(v.y); b.z = f2bf(v.z); b.w = f2bf(v.w);
    int boff = (kk << 1) ^ ((row & 7) << 4);
    *(ushort4*)((char*)xs + row * 256 + boff) = b;
  }
  __syncthreads();
  const int wid = t >> 6, lane = t & 63;
  const int m16 = lane & 15, kg = lane >> 4;
  const int arow = wid * 16 + m16;
  const f32x4 vzero = {0.f, 0.f, 0.f, 0.f};
  f32x4 acc[8];
#pragma unroll
  for (int i = 0; i < 8; ++i) acc[i] = vzero;
#pragma unroll
  for (int s = 0; s < 4; ++s) {
    int kb = s * 64 + kg * 16;
    bf16x8 a = *(const bf16x8*)((const char*)xs + arow * 256 + (kb ^ ((arow & 7) << 4)));
#pragma unroll
    for (int cf = 0; cf < 8; ++cf) {
      int wrow = cf * 16 + m16;
      bf16x8 b = *(const bf16x8*)((const char*)wl + wrow * 256 + (kb ^ ((wrow & 7) << 4)));
      acc[cf] = __builtin_amdgcn_mfma_f32_16x16x32_bf16(a, b, acc[cf], 0, 0, 0);
    }
  }
  // C/D layout: col = cf*16 + (lane&15), row = wid*16 + (lane>>4)*4 + q
  const int crow0 = wid * 16 + kg * 4;
#pragma unroll
  for (int q = 0; q < 4; ++q) {
    int gr = r0 + crow0 + q;
    if (gr < n) {
#pragma unroll
      for (int cf = 0; cf < 8; ++cf)
        xl[gr * 128 + cf * 16 + m16] = f2bf(acc[cf][q]);
    }
  }
  // ---- fused ai/aj epilogue ----
  float ati[8], atj[8];
#pragma unroll
  for (int cf = 0; cf < 8; ++cf) {
    ati[cf] = att_i[cf * 16 + m16];
    atj[cf] = att_j[cf * 16 + m16];
  }
  float4 aemi0 = *(const float4*)(att_em_i + m16 * 8);
  float4 aemi1 = *(const float4*)(att_em_i + m16 * 8 + 4);
  float4 aemj0 = *(const float4*)(att_em_j + m16 * 8);
  float4 aemj1 = *(const float4*)(att_em_j + m16 * 8 + 4);
#pragma unroll
  for (int q = 0; q < 4; ++q) {
    int gr = r0 + crow0 + q;
    if (gr < n) {
      float si = 0.f, sj = 0.f;
#pragma unroll
      for (int cf = 0; cf < 8; ++cf) {
        si += acc[cf][q] * ati[cf];
        sj += acc[cf][q] * atj[cf];
      }
      const float* ep = emb + (size_t)gr * 128 + m16 * 8;
      float4 e0 = *(const float4*)(ep);
      float4 e1 = *(const float4*)(ep + 4);
      si += e0.x * aemi0.x + e0.y * aemi0.y + e0.z * aemi0.z + e0.w * aemi0.w
          + e1.x * aemi1.x + e1.y * aemi1.y + e1.z * aemi1.z + e1.w * aemi1.w;
      sj += e0.x * aemj0.x + e0.y * aemj0.y + e0.z * aemj0.z + e0.w * aemj0.w
          + e1.x * aemj1.x + e1.y * aemj1.y + e1.z * aemj1.z + e1.w * aemj1.w;
#pragma unroll
      for (int off = 1; off < 16; off <<= 1) {
        si += __shfl_xor(si, off);
        sj += __shfl_xor(sj, off);
      }
      if (m16 == 0) { ai[gr] = si; aj[gr] = sj; }
    }
  }
}

// ---------------- CSR build ----------------
__global__ __launch_bounds__(256) void count_rank_kernel(
    const int* __restrict__ dst, int* __restrict__ cnt, int* __restrict__ pw, int E) {
  int e = (blockIdx.x * blockDim.x + threadIdx.x) * 4;
  if (e + 3 < E) {
    int4 d4 = *(const int4*)(dst + e);
    int4 p4;
    p4.x = atomicAdd(&cnt[d4.x], 1);
    p4.y = atomicAdd(&cnt[d4.y], 1);
    p4.z = atomicAdd(&cnt[d4.z], 1);
    p4.w = atomicAdd(&cnt[d4.w], 1);
    *(int4*)(pw + e) = p4;
  } else {
    for (; e < E; ++e) pw[e] = atomicAdd(&cnt[dst[e]], 1);
  }
}

// multi-block scan, step 1: per-block exclusive scan + block sums
__global__ __launch_bounds__(1024) void scan1_kernel(
    const int* __restrict__ cnt, int* __restrict__ rp, int* __restrict__ bsum, int n) {
  __shared__ int wsum[16];
  int t = threadIdx.x, lane = t & 63, wid = t >> 6;
  int i = blockIdx.x * 1024 + t;
  int v = (i < n) ? cnt[i] : 0;
  int incl = v;
#pragma unroll
  for (int off = 1; off < 64; off <<= 1) {
    int u = __shfl_up(incl, off);
    if (lane >= off) incl += u;
  }
  if (lane == 63) wsum[wid] = incl;
  __syncthreads();
  if (t < 16) {
    int wv = wsum[t];
    int winc = wv;
#pragma unroll
    for (int off = 1; off < 16; off <<= 1) {
      int u = __shfl_up(winc, off);
      if (t >= off) winc += u;
    }
    wsum[t] = winc - wv;  // exclusive wave offset
  }
  __syncthreads();
  int excl = wsum[wid] + incl - v;
  if (i < n) rp[i] = excl;
  if (t == 1023) bsum[blockIdx.x] = excl + v;
}

// step 2: scan block sums (single 64-lane block), write total to rp[n]
__global__ __launch_bounds__(64) void scan2_kernel(
    int* __restrict__ bsum, int* __restrict__ rp, int nb, int n) {
  int t = threadIdx.x;
  int carry = 0;
  for (int base = 0; base < nb; base += 64) {
    int idx = base + t;
    int v = (idx < nb) ? bsum[idx] : 0;
    int incl = v;
#pragma unroll
    for (int off = 1; off < 64; off <<= 1) {
      int u = __shfl_up(incl, off);
      if (t >= off) incl += u;
    }
    if (idx < nb) bsum[idx] = carry + incl - v;
    carry += __shfl(incl, 63);
  }
  if (t == 0) rp[n] = carry;
}

// step 3: add block offsets
__global__ __launch_bounds__(256) void scan3_kernel(
    const int* __restrict__ bsum, int* __restrict__ rp, int n) {
  int i = blockIdx.x * blockDim.x + threadIdx.x;
  if (i < n) rp[i] += bsum[i >> 10];
}

// atomic-free scatter: pos = rp[dst] + precomputed rank; 4 edges/thread
__global__ __launch_bounds__(256) void scatter_kernel(
    const int* __restrict__ src, const int* __restrict__ dst,
    const int* __restrict__ rp, const int* __restrict__ pw,
    int* __restrict__ csr, int E) {
  int e = (blockIdx.x * blockDim.x + threadIdx.x) * 4;
  if (e + 3 < E) {
    int4 s4 = *(const int4*)(src + e);
    int4 d4 = *(const int4*)(dst + e);
    int4 p4 = *(const int4*)(pw + e);
    int r0 = rp[d4.x], r1 = rp[d4.y], r2 = rp[d4.z], r3 = rp[d4.w];
    csr[r0 + p4.x] = s4.x;
    csr[r1 + p4.y] = s4.y;
    csr[r2 + p4.z] = s4.z;
    csr[r3 + p4.w] = s4.w;
  } else {
    for (; e < E; ++e) csr[rp[dst[e]] + pw[e]] = src[e];
  }
}

// ---------------- fused segment-softmax + aggregation: one wave per node ----------------
__global__ __launch_bounds__(256) void agg_kernel(
    const float* __restrict__ ai, const float* __restrict__ aj,
    const unsigned short* __restrict__ xl,
    const int* __restrict__ row_ptr, const int* __restrict__ csr_src,
    const float* __restrict__ bias, float* __restrict__ out, int n) {
  int wid = threadIdx.x >> 6, lane = threadIdx.x & 63;
  int node = blockIdx.x * 4 + wid;
  if (node >= n) return;
  int beg = row_ptr[node], end = row_ptr[node + 1];
  float ain = ai[node];
  float w_self = __expf(lrelu(ain + aj[node]));
  float dl = 0.f;
  float acc0 = 0.f, acc1 = 0.f;
  const int c0 = lane * 2;
  for (int cs = beg; cs < end; cs += 64) {
    int ce = min(64, end - cs);
    int s = 0;
    float we = 0.f;
    if (lane < ce) {
      s = csr_src[cs + lane];
      we = __expf(lrelu(ain + aj[s]));
    }
    dl += we;
    int j = 0;
    for (; j + 8 <= ce; j += 8) {
      float w0 = __shfl(we, j),     w1 = __shfl(we, j + 1);
      float w2 = __shfl(we, j + 2), w3 = __shfl(we, j + 3);
      float w4 = __shfl(we, j + 4), w5 = __shfl(we, j + 5);
      float w6 = __shfl(we, j + 6), w7 = __shfl(we, j + 7);
      int i0 = __shfl(s, j),     i1 = __shfl(s, j + 1);
      int i2 = __shfl(s, j + 2), i3 = __shfl(s, j + 3);
      int i4 = __shfl(s, j + 4), i5 = __shfl(s, j + 5);
      int i6 = __shfl(s, j + 6), i7 = __shfl(s, j + 7);
      ushort2 v0 = *(const ushort2*)(xl + (size_t)i0 * 128 + c0);
      ushort2 v1 = *(const ushort2*)(xl + (size_t)i1 * 128 + c0);
      ushort2 v2 = *(const ushort2*)(xl + (size_t)i2 * 128 + c0);
      ushort2 v3 = *(const ushort2*)(xl + (size_t)i3 * 128 + c0);
      ushort2 v4 = *(const ushort2*)(xl + (size_t)i4 * 128 + c0);
      ushort2 v5 = *(const ushort2*)(xl + (size_t)i5 * 128 + c0);
      ushort2 v6 = *(const ushort2*)(xl + (size_t)i6 * 128 + c0);
      ushort2 v7 = *(const ushort2*)(xl + (size_t)i7 * 128 + c0);
      acc0 += w0 * bf2f(v0.x); acc1 += w0 * bf2f(v0.y);
      acc0 += w1 * bf2f(v1.x); acc1 += w1 * bf2f(v1.y);
      acc0 += w2 * bf2f(v2.x); acc1 += w2 * bf2f(v2.y);
      acc0 += w3 * bf2f(v3.x); acc1 += w3 * bf2f(v3.y);
      acc0 += w4 * bf2f(v4.x); acc1 += w4 * bf2f(v4.y);
      acc0 += w5 * bf2f(v5.x); acc1 += w5 * bf2f(v5.y);
      acc0 += w6 * bf2f(v6.x); acc1 += w6 * bf2f(v6.y);
      acc0 += w7 * bf2f(v7.x); acc1 += w7 * bf2f(v7.y);
    }
    for (; j < ce; ++j) {
      float wj = __shfl(we, j);
      int ij = __shfl(s, j);
      ushort2 v = *(const ushort2*)(xl + (size_t)ij * 128 + c0);
      acc0 += wj * bf2f(v.x); acc1 += wj * bf2f(v.y);
    }
  }
#pragma unroll
  for (int off = 32; off > 0; off >>= 1) dl += __shfl_xor(dl, off);
  float inv = 1.f / (dl + w_self + 1e-16f);
  ushort2 u = *(const ushort2*)(xl + (size_t)node * 128 + c0);
  float2 o;
  o.x = (acc0 + w_self * bf2f(u.x)) * inv + bias[c0];
  o.y = (acc1 + w_self * bf2f(u.y)) * inv + bias[c0 + 1];
  *(float2*)(out + (size_t)node * 128 + c0) = o;
}

// ---------------- BatchNorm stats: two-stage tree reduce, NO atomics ----------------
// Stage A: block b covers rows [b*32, b*32+32); partials transposed: pS[c*BN_PS+b]
__global__ __launch_bounds__(256) void bnstat_a_kernel(
    const float* __restrict__ out, float* __restrict__ pS, float* __restrict__ pQ,
    int n) {
  __shared__ float4 red_s[8][32];
  __shared__ float4 red_q[8][32];
  int q = threadIdx.x & 31;      // column quad: cols 4q..4q+3
  int rs = threadIdx.x >> 5;     // row slot 0..7
  int rbase = blockIdx.x * 32;
  float4 s = {0.f, 0.f, 0.f, 0.f}, ss = {0.f, 0.f, 0.f, 0.f};
#pragma unroll
  for (int k = 0; k < 4; ++k) {
    int r = rbase + rs + k * 8;
    if (r < n) {
      float4 v = *(const float4*)(out + (size_t)r * 128 + q * 4);
      s.x += v.x; s.y += v.y; s.z += v.z; s.w += v.w;
      ss.x += v.x * v.x; ss.y += v.y * v.y; ss.z += v.z * v.z; ss.w += v.w * v.w;
    }
  }
  red_s[rs][q] = s;
  red_q[rs][q] = ss;
  __syncthreads();
  if (threadIdx.x < 32) {
    float4 ts = red_s[0][threadIdx.x], tq = red_q[0][threadIdx.x];
#pragma unroll
    for (int k = 1; k < 8; ++k) {
      float4 a = red_s[k][threadIdx.x], b = red_q[k][threadIdx.x];
      ts.x += a.x; ts.y += a.y; ts.z += a.z; ts.w += a.w;
      tq.x += b.x; tq.y += b.y; tq.z += b.z; tq.w += b.w;
    }
    int c = threadIdx.x * 4;
    int b = blockIdx.x;
    pS[(c + 0) * BN_PS + b] = ts.x; pS[(c + 1) * BN_PS + b] = ts.y;
    pS[(c + 2) * BN_PS + b] = ts.z; pS[(c + 3) * BN_PS + b] = ts.w;
    pQ[(c + 0) * BN_PS + b] = tq.x; pQ[(c + 1) * BN_PS + b] = tq.y;
    pQ[(c + 2) * BN_PS + b] = tq.z; pQ[(c + 3) * BN_PS + b] = tq.w;
  }
}

// Stage B: one block per column; contiguous reduce of nb partials
__global__ __launch_bounds__(256) void bnstat_b_kernel(
    const float* __restrict__ pS, const float* __restrict__ pQ,
    float* __restrict__ sums, float* __restrict__ sumsq, int nb) {
  __shared__ float ws_s[4], ws_q[4];
  int c = blockIdx.x;
  int t = threadIdx.x, lane = t & 63, wid = t >> 6;
  const float* rowS = pS + (size_t)c * BN_PS;
  const float* rowQ = pQ + (size_t)c * BN_PS;
  float s = 0.f, qv = 0.f;
  for (int i = t; i < nb; i += 256) {
    s += rowS[i];
    qv += rowQ[i];
  }
#pragma unroll
  for (int off = 32; off > 0; off >>= 1) {
    s += __shfl_xor(s, off);
    qv += __shfl_xor(qv, off);
  }
  if (lane == 0) { ws_s[wid] = s; ws_q[wid] = qv; }
  __syncthreads();
  if (t == 0) {
    sums[c] = ws_s[0] + ws_s[1] + ws_s[2] + ws_s[3];
    sumsq[c] = ws_q[0] + ws_q[1] + ws_q[2] + ws_q[3];
  }
}

__global__ __launch_bounds__(256) void bnapply_kernel(
    float* __restrict__ out, const float* __restrict__ sums,
    const float* __restrict__ sumsq, const float* __restrict__ gamma,
    const float* __restrict__ beta, int n, float invN) {
  int q = threadIdx.x & 31;
  int rs = threadIdx.x >> 5;
  int c = q * 4;
  float4 mu, var, sc, sh;
  mu.x = sums[c + 0] * invN; mu.y = sums[c + 1] * invN;
  mu.z = sums[c + 2] * invN; mu.w = sums[c + 3] * invN;
  var.x = sumsq[c + 0] * invN - mu.x * mu.x;
  var.y = sumsq[c + 1] * invN - mu.y * mu.y;
  var.z = sumsq[c + 2] * invN - mu.z * mu.z;
  var.w = sumsq[c + 3] * invN - mu.w * mu.w;
  sc.x = rsqrtf(var.x + 1e-5f) * gamma[c + 0];
  sc.y = rsqrtf(var.y + 1e-5f) * gamma[c + 1];
  sc.z = rsqrtf(var.z + 1e-5f) * gamma[c + 2];
  sc.w = rsqrtf(var.w + 1e-5f) * gamma[c + 3];
  sh.x = beta[c + 0] - mu.x * sc.x;
  sh.y = beta[c + 1] - mu.y * sc.y;
  sh.z = beta[c + 2] - mu.z * sc.z;
  sh.w = beta[c + 3] - mu.w * sc.w;
  for (int r = blockIdx.x * 8 + rs; r < n; r += gridDim.x * 8) {
    float4 v = *(const float4*)(out + (size_t)r * 128 + c);
    v.x = v.x * sc.x + sh.x;
    v.y = v.y * sc.y + sh.y;
    v.z = v.z * sc.z + sh.z;
    v.w = v.w * sc.w + sh.w;
    *(float4*)(out + (size_t)r * 128 + c) = v;
  }
}

extern "C" void kernel_launch(void* const* d_in, const int* in_sizes, int n_in,
                              void* d_out, int out_size, void* d_ws, size_t ws_size,
                              hipStream_t stream) {
  (void)n_in; (void)out_size; (void)ws_size;
  const float* x = (const float*)d_in[0];
  const int* ei = (const int*)d_in[1];
  const float* emb = (const float*)d_in[2];
  const float* lin_w = (const float*)d_in[3];
  const float* att_i = (const float*)d_in[4];
  const float* att_j = (const float*)d_in[5];
  const float* att_em_i = (const float*)d_in[6];
  const float* att_em_j = (const float*)d_in[7];
  const float* bias = (const float*)d_in[8];
  const float* gamma = (const float*)d_in[9];
  const float* beta = (const float*)d_in[10];
  float* out = (float*)d_out;
  const int N = in_sizes[0] / 128;
  const int E = in_sizes[1] / 2;
  const int* src = ei;
  const int* dst = ei + E;
  const int NB = (N + 1023) / 1024;
  const int NBA = (N + 31) / 32;  // bnstat stage-A blocks (<= BN_PS)

  auto align_up = [](size_t v) { return (v + 255) & ~(size_t)255; };
  size_t off = 0;
  size_t xl_off = off;    off = align_up(off + (size_t)N * 128 * 2);
  size_t ai_off = off;    off = align_up(off + (size_t)N * 4);
  size_t aj_off = off;    off = align_up(off + (size_t)N * 4);
  size_t rp_off = off;    off = align_up(off + (size_t)(N + 1) * 4);
  size_t csr_off = off;   off = align_up(off + (size_t)E * 4);
  size_t pw_off = off;    off = align_up(off + (size_t)E * 4);
  size_t bsum_off = off;  off = align_up(off + (size_t)(NB + 1) * 4);
  size_t pS_off = off;    off = align_up(off + (size_t)128 * BN_PS * 4);
  size_t pQ_off = off;    off = align_up(off + (size_t)128 * BN_PS * 4);
  size_t sums_off = off;  off = align_up(off + 512);
  size_t sumsq_off = off; off = align_up(off + 512);
  size_t cnt_off = off;   off = align_up(off + (size_t)N * 4);

  char* ws = (char*)d_ws;
  unsigned short* xl = (unsigned short*)(ws + xl_off);
  float* ai = (float*)(ws + ai_off);
  float* aj = (float*)(ws + aj_off);
  int* rp = (int*)(ws + rp_off);
  int* csr = (int*)(ws + csr_off);
  int* pw = (int*)(ws + pw_off);
  int* bsum = (int*)(ws + bsum_off);
  float* pS = (float*)(ws + pS_off);
  float* pQ = (float*)(ws + pQ_off);
  float* sums = (float*)(ws + sums_off);
  float* sumsq = (float*)(ws + sumsq_off);
  int* cnt = (int*)(ws + cnt_off);

  // zero cnt only (count_rank needs zeros; everything else fully written)
  hipLaunchKernelGGL(zero_kernel, dim3((N + 255) / 256), dim3(256), 0, stream,
                     cnt, N);
  hipLaunchKernelGGL(gemm_kernel, dim3((N + 63) / 64), dim3(256), 0, stream,
                     x, lin_w, emb, att_i, att_j, att_em_i, att_em_j,
                     xl, ai, aj, N);
  hipLaunchKernelGGL(count_rank_kernel, dim3((E / 4 + 255) / 256), dim3(256), 0, stream,
                     dst, cnt, pw, E);
  hipLaunchKernelGGL(scan1_kernel, dim3(NB), dim3(1024), 0, stream, cnt, rp, bsum, N);
  hipLaunchKernelGGL(scan2_kernel, dim3(1), dim3(64), 0, stream, bsum, rp, NB, N);
  hipLaunchKernelGGL(scan3_kernel, dim3((N + 255) / 256), dim3(256), 0, stream,
                     bsum, rp, N);
  hipLaunchKernelGGL(scatter_kernel, dim3((E / 4 + 255) / 256), dim3(256), 0, stream,
                     src, dst, rp, pw, csr, E);
  hipLaunchKernelGGL(agg_kernel, dim3((N + 3) / 4), dim3(256), 0, stream,
                     ai, aj, xl, rp, csr, bias, out, N);
  hipLaunchKernelGGL(bnstat_a_kernel, dim3(NBA), dim3(256), 0, stream,
                     out, pS, pQ, N);
  hipLaunchKernelGGL(bnstat_b_kernel, dim3(128), dim3(256), 0, stream,
                     pS, pQ, sums, sumsq, NBA);
  hipLaunchKernelGGL(bnapply_kernel, dim3(2048), dim3(256), 0, stream,
                     out, sums, sumsq, gamma, beta, N, 1.0f / (float)N);
}